// Round 13
// baseline (629.466 us; speedup 1.0000x reference)
//
#include <hip/hip_runtime.h>
#include <math.h>

#define N_NODES 200000
#define N_EDGES 5000000
#define NFEAT 16
#define DIM 10
#define NGRAPH 1000
#define BSH 8            // 256 nodes per dst bucket
#define BNODES 256
#define NB ((N_NODES + BNODES - 1) / BNODES)   // 782
#define NBLK 512         // hist/scatter blocks
#define STB 512          // hist/scatter block size

// split bf16 tables: tA[i] = uint4 (dims 0..7, 16B aligned), tB[i] = u32 (dims 8..9)
// total 20B/node -> 4.0MB, per-XCD-L2-fit, and the 16B part loads as ONE dwordx4.

// pack two f32 -> two bf16 (RNE) in one u32
__device__ __forceinline__ unsigned pkbf(float a, float b) {
    unsigned ua = __float_as_uint(a), ub = __float_as_uint(b);
    ua = (ua + 0x7fffu + ((ua >> 16) & 1u)) >> 16;
    ub = (ub + 0x7fffu + ((ub >> 16) & 1u)) >> 16;
    return ua | (ub << 16);
}
__device__ __forceinline__ float uplo(unsigned u) { return __uint_as_float(u << 16); }
__device__ __forceinline__ float uphi(unsigned u) { return __uint_as_float(u & 0xffff0000u); }

// ---------- pass 1: per-block bucket histogram + global bucket totals ----------
__global__ void __launch_bounds__(STB)
khist(const int* __restrict__ dst, unsigned* __restrict__ histg,
      unsigned* __restrict__ tot) {
    __shared__ int h[NB];
    for (int t = threadIdx.x; t < NB; t += STB) h[t] = 0;
    __syncthreads();
    int per = (N_EDGES + NBLK - 1) / NBLK;
    int e0 = blockIdx.x * per;
    int e1 = e0 + per; if (e1 > N_EDGES) e1 = N_EDGES;
    int e = e0 + threadIdx.x;
    for (; e + 7 * STB < e1; e += 8 * STB) {
        int d[8];
#pragma unroll
        for (int k = 0; k < 8; ++k) d[k] = __builtin_nontemporal_load(&dst[e + k * STB]);
#pragma unroll
        for (int k = 0; k < 8; ++k) atomicAdd(&h[d[k] >> BSH], 1);
    }
    for (; e < e1; e += STB)
        atomicAdd(&h[__builtin_nontemporal_load(&dst[e]) >> BSH], 1);
    __syncthreads();
    for (int t = threadIdx.x; t < NB; t += STB) {
        int c = h[t];
        histg[(size_t)blockIdx.x * NB + t] = c;
        if (c) atomicAdd(&tot[t], (unsigned)c);
    }
}

// ---------- pass 2a: exclusive scan of 782 bucket totals -> bstart ----------
__global__ void __launch_bounds__(1024)
kscan_tot(const unsigned* __restrict__ tot, int* __restrict__ bstart) {
    __shared__ int s[NB];
    int t = threadIdx.x;
    if (t < NB) s[t] = tot[t];
    __syncthreads();
    if (t == 0) {
        int acc = 0;
        for (int i = 0; i < NB; ++i) { int c = s[i]; s[i] = acc; acc += c; }
    }
    __syncthreads();
    if (t < NB) bstart[t] = s[t];
    if (t == 0) bstart[NB] = N_EDGES;
}

// ---------- pass 2b: per-bucket block-scan of per-block counts -> write bases ----------
__global__ void __launch_bounds__(STB)
kscan_wb(unsigned* __restrict__ histg, const int* __restrict__ bstart) {
    int t = blockIdx.x;           // bucket
    int tid = threadIdx.x;        // source block
    int lane = tid & 63, wv = tid >> 6;
    unsigned v = histg[(size_t)tid * NB + t];
    unsigned orig = v;
    // inclusive wave scan
#pragma unroll
    for (int m = 1; m < 64; m <<= 1) {
        unsigned u = __shfl(v, lane - m, 64);
        if (lane >= m) v += u;
    }
    __shared__ unsigned wtot[8];
    __shared__ unsigned wbase[8];
    if (lane == 63) wtot[wv] = v;
    __syncthreads();
    if (tid == 0) {
        unsigned acc = 0;
        for (int w = 0; w < 8; ++w) { wbase[w] = acc; acc += wtot[w]; }
    }
    __syncthreads();
    unsigned excl = v - orig + wbase[wv];
    histg[(size_t)tid * NB + t] = (unsigned)bstart[t] + excl;
}

// ---------- pass 3: single-pass scatter from precomputed bases ----------
__global__ void __launch_bounds__(STB)
kscatter(const int* __restrict__ src, const int* __restrict__ dst,
         const unsigned* __restrict__ histg, unsigned* __restrict__ packed) {
    __shared__ int wp[NB];
    for (int t = threadIdx.x; t < NB; t += STB)
        wp[t] = histg[(size_t)blockIdx.x * NB + t];
    __syncthreads();
    int per = (N_EDGES + NBLK - 1) / NBLK;
    int e0 = blockIdx.x * per;
    int e1 = e0 + per; if (e1 > N_EDGES) e1 = N_EDGES;
    int e = e0 + threadIdx.x;
    for (; e + 7 * STB < e1; e += 8 * STB) {
        int d[8], s[8];
#pragma unroll
        for (int k = 0; k < 8; ++k) {
            d[k] = __builtin_nontemporal_load(&dst[e + k * STB]);
            s[k] = __builtin_nontemporal_load(&src[e + k * STB]);
        }
#pragma unroll
        for (int k = 0; k < 8; ++k) {
            int r = atomicAdd(&wp[d[k] >> BSH], 1);
            __builtin_nontemporal_store(((unsigned)s[k] << BSH) | (unsigned)(d[k] & (BNODES - 1)),
                                        &packed[r]);
        }
    }
    for (; e < e1; e += STB) {
        int dv = __builtin_nontemporal_load(&dst[e]);
        int sv = __builtin_nontemporal_load(&src[e]);
        int r = atomicAdd(&wp[dv >> BSH], 1);
        __builtin_nontemporal_store(((unsigned)sv << BSH) | (unsigned)(dv & (BNODES - 1)),
                                    &packed[r]);
    }
}

// ---------- pass 4: per-bucket counting sort by dstLocal -> per-node CSR ----------
__global__ void __launch_bounds__(BNODES)
node_sort(const unsigned* __restrict__ pin, const int* __restrict__ bstart,
          unsigned* __restrict__ ecol, int* __restrict__ rowstart) {
    __shared__ int cnt[BNODES];
    __shared__ int cur[BNODES];
    int b = blockIdx.x;
    int e0 = bstart[b], e1 = bstart[b + 1];
    int tid = threadIdx.x;
    cnt[tid] = 0;
    __syncthreads();
    int e = e0 + tid;
    for (; e + 7 * BNODES < e1; e += 8 * BNODES) {
        unsigned p[8];
#pragma unroll
        for (int k = 0; k < 8; ++k) p[k] = __builtin_nontemporal_load(&pin[e + k * BNODES]);
#pragma unroll
        for (int k = 0; k < 8; ++k) atomicAdd(&cnt[p[k] & (BNODES - 1)], 1);
    }
    for (; e < e1; e += BNODES)
        atomicAdd(&cnt[__builtin_nontemporal_load(&pin[e]) & (BNODES - 1)], 1);
    __syncthreads();
    if (tid == 0) {
        int acc = 0;
        for (int t = 0; t < BNODES; ++t) { int c = cnt[t]; cur[t] = acc; acc += c; }
    }
    __syncthreads();
    int n0 = b << BSH;
    if (n0 + tid < N_NODES) rowstart[n0 + tid] = e0 + cur[tid];
    if (b == 0 && tid == 0) rowstart[N_NODES] = N_EDGES;
    e = e0 + tid;
    for (; e + 3 * BNODES < e1; e += 4 * BNODES) {
        unsigned p[4];
#pragma unroll
        for (int k = 0; k < 4; ++k) p[k] = __builtin_nontemporal_load(&pin[e + k * BNODES]);
#pragma unroll
        for (int k = 0; k < 4; ++k) {
            int slot = atomicAdd(&cur[p[k] & (BNODES - 1)], 1);
            ecol[e0 + slot] = p[k] >> BSH;
        }
    }
    for (; e < e1; e += BNODES) {
        unsigned p = __builtin_nontemporal_load(&pin[e]);
        int slot = atomicAdd(&cur[p & (BNODES - 1)], 1);
        ecol[e0 + slot] = p >> BSH;
    }
}

// ---------- y = x @ w1_1 -> split bf16 tables ----------
__global__ void xform_kernel(const float* __restrict__ x,
                             const float* __restrict__ w1,   // [16][10]
                             unsigned* __restrict__ tA,      // [N*4] u32 (16B-aligned rows)
                             unsigned* __restrict__ tB) {    // [N] u32
    int i = blockIdx.x * blockDim.x + threadIdx.x;
    if (i >= N_NODES) return;
    float xi[NFEAT];
    const float4* xr = reinterpret_cast<const float4*>(x + (size_t)i * NFEAT);
#pragma unroll
    for (int q = 0; q < 4; q++) {
        float4 v = xr[q];
        xi[q*4+0] = v.x; xi[q*4+1] = v.y; xi[q*4+2] = v.z; xi[q*4+3] = v.w;
    }
    float o[DIM];
#pragma unroll
    for (int j = 0; j < DIM; j++) {
        float s = 0.f;
#pragma unroll
        for (int f = 0; f < NFEAT; f++) s += xi[f] * w1[f * DIM + j];
        o[j] = s;
    }
#pragma unroll
    for (int k = 0; k < 4; ++k)
        __builtin_nontemporal_store(pkbf(o[2*k], o[2*k+1]), &tA[(size_t)i * 4 + k]);
    __builtin_nontemporal_store(pkbf(o[8], o[9]), &tB[i]);
}

// ---------- edge-owner gather + MLP + pool, split-table loads ----------
// Each lane owns one edge; per edge: ONE dwordx4 (aligned) + ONE dword.
// Mean degree 25 -> each of 16 lanes owns 1-2 edges; concurrency = lanes x waves.
template <bool FIRST>
__global__ void __launch_bounds__(256, 8)
gin_gatherE(const uint4* __restrict__ tA, const unsigned* __restrict__ tB,
            const int* __restrict__ rowstart,
            const unsigned* __restrict__ ecol,
            const float* __restrict__ w1, const float* __restrict__ b1,
            const float* __restrict__ w2, const float* __restrict__ b2,
            const int* __restrict__ batch,
            unsigned* __restrict__ oA, unsigned* __restrict__ oB,
            float* __restrict__ pooled) {
    __shared__ float hp[16][DIM];
    __shared__ int gid[16];
    int tid = threadIdx.x;
    int grp = tid >> 4;
    int j = tid & 15;
    int lane = tid & 63;
    int base = lane & 48;
    int i = blockIdx.x * 16 + grp;

    int r0 = rowstart[i];
    int r1 = rowstart[i + 1];

    float a[DIM];
#pragma unroll
    for (int d = 0; d < DIM; ++d) a[d] = 0.f;

    int idx = r0 + j;
    for (; idx + 16 < r1; idx += 32) {
        unsigned sA = __builtin_nontemporal_load(&ecol[idx]);
        unsigned sB = __builtin_nontemporal_load(&ecol[idx + 16]);
        uint4 A0 = tA[sA]; unsigned B0 = tB[sA];
        uint4 A1 = tA[sB]; unsigned B1 = tB[sB];
        a[0] += uplo(A0.x) + uplo(A1.x); a[1] += uphi(A0.x) + uphi(A1.x);
        a[2] += uplo(A0.y) + uplo(A1.y); a[3] += uphi(A0.y) + uphi(A1.y);
        a[4] += uplo(A0.z) + uplo(A1.z); a[5] += uphi(A0.z) + uphi(A1.z);
        a[6] += uplo(A0.w) + uplo(A1.w); a[7] += uphi(A0.w) + uphi(A1.w);
        a[8] += uplo(B0)   + uplo(B1);   a[9] += uphi(B0)   + uphi(B1);
    }
    if (idx < r1) {
        unsigned sA = __builtin_nontemporal_load(&ecol[idx]);
        uint4 A0 = tA[sA]; unsigned B0 = tB[sA];
        a[0] += uplo(A0.x); a[1] += uphi(A0.x);
        a[2] += uplo(A0.y); a[3] += uphi(A0.y);
        a[4] += uplo(A0.z); a[5] += uphi(A0.z);
        a[6] += uplo(A0.w); a[7] += uphi(A0.w);
        a[8] += uplo(B0);   a[9] += uphi(B0);
    }

    // butterfly reduce across the 16-lane group
#pragma unroll
    for (int m = 1; m <= 8; m <<= 1) {
#pragma unroll
        for (int d = 0; d < DIM; ++d) a[d] += __shfl_xor(a[d], m, 64);
    }

    // own row (group-uniform -> broadcast)
    uint4 Ai = tA[i]; unsigned Bi = tB[i];
    float z[DIM];
    z[0] = uplo(Ai.x) + a[0]; z[1] = uphi(Ai.x) + a[1];
    z[2] = uplo(Ai.y) + a[2]; z[3] = uphi(Ai.y) + a[3];
    z[4] = uplo(Ai.z) + a[4]; z[5] = uphi(Ai.z) + a[5];
    z[6] = uplo(Ai.w) + a[6]; z[7] = uphi(Ai.w) + a[7];
    z[8] = uplo(Bi)   + a[8]; z[9] = uphi(Bi)   + a[9];

    float t1v = 0.f;
    if (FIRST) {
        if (j < DIM) {
            float s1 = z[j] + b1[j];
            t1v = s1 > 0.f ? s1 : 0.f;
        }
    } else {
        if (j < DIM) {
            float s1 = b1[j];
#pragma unroll
            for (int f = 0; f < DIM; ++f) s1 += z[f] * w1[f * DIM + j];
            t1v = s1 > 0.f ? s1 : 0.f;
        }
    }
    float s2 = (j < DIM) ? b2[j] : 0.f;
#pragma unroll
    for (int f = 0; f < DIM; ++f) {
        float tf = __shfl(t1v, base + f, 64);
        if (j < DIM) s2 += tf * w2[f * DIM + j];
    }
    float hv = s2 > 0.f ? s2 : 0.f;

    // even lanes j<10 pack (hv_j, hv_{j+1}); j<8 -> word j/2 of oA[i], j==8 -> oB[i]
    float hnext = __shfl(hv, base + ((j + 1) & 15), 64);
    if (j < DIM && !(j & 1)) {
        unsigned wword = pkbf(hv, hnext);
        if (j < 8) __builtin_nontemporal_store(wword, &oA[(size_t)i * 4 + (j >> 1)]);
        else       __builtin_nontemporal_store(wword, &oB[i]);
    }

    if (j < DIM) hp[grp][j] = hv;
    if (j == 0) gid[grp] = batch[i];
    __syncthreads();

    if (tid < DIM) {
        int cg = gid[0];
        float s = hp[0][tid];
        for (int n = 1; n < 16; ++n) {
            int g = gid[n];
            float v = hp[n][tid];
            if (g == cg) s += v;
            else { atomicAdd(&pooled[cg * DIM + tid], s); cg = g; s = v; }
        }
        atomicAdd(&pooled[cg * DIM + tid], s);
    }
}

// ---------- readout ----------
__global__ void final_kernel(const float* __restrict__ pooled,  // [5][G][10]
                             const int* __restrict__ batch,
                             const float* __restrict__ lw,      // [5][10]
                             float* __restrict__ out) {
    int g = blockIdx.x * blockDim.x + threadIdx.x;
    if (g >= NGRAPH) return;
    int lo = 0, hi = N_NODES;
    while (lo < hi) { int m = (lo + hi) >> 1; if (batch[m] < g) lo = m + 1; else hi = m; }
    int a = lo;
    hi = N_NODES;
    while (lo < hi) { int m = (lo + hi) >> 1; if (batch[m] < g + 1) lo = m + 1; else hi = m; }
    float c = (float)(lo - a);
    float inv = 1.0f / (c > 1.f ? c : 1.f);
    float s = 0.f;
#pragma unroll
    for (int l = 0; l < 5; l++) {
        float d = 0.f;
#pragma unroll
        for (int j = 0; j < DIM; j++)
            d += pooled[(size_t)l * NGRAPH * DIM + (size_t)g * DIM + j] * lw[l * DIM + j];
        s += d * inv;
    }
    out[g] = 1.0f / (1.0f + expf(-s));
}

extern "C" void kernel_launch(void* const* d_in, const int* in_sizes, int n_in,
                              void* d_out, int out_size, void* d_ws, size_t ws_size,
                              hipStream_t stream) {
    const float* x    = (const float*)d_in[0];
    const int*   ei   = (const int*)d_in[1];
    const int*   batch= (const int*)d_in[2];
    const float* w1_1 = (const float*)d_in[3];
    const float* b1_1 = (const float*)d_in[4];
    const float* w2_1 = (const float*)d_in[5];
    const float* b2_1 = (const float*)d_in[6];
    const float* ws1  = (const float*)d_in[7];   // [4][10][10]
    const float* bs1  = (const float*)d_in[8];   // [4][10]
    const float* ws2  = (const float*)d_in[9];   // [4][10][10]
    const float* bs2  = (const float*)d_in[10];  // [4][10]
    const float* lw   = (const float*)d_in[11];  // [5][10]
    float* out = (float*)d_out;

    const int* src = ei;
    const int* dst = ei + N_EDGES;

    // ---- workspace layout (u32 units; 16B-aligned table sections) ----
    int* bstart      = (int*)d_ws;                      // [NB+1]     @0
    unsigned* tot    = (unsigned*)d_ws + 784;           // [NB]       @784
    int* rowstart    = (int*)d_ws + 1568;               // [N+1]      @1568
    unsigned* histg  = (unsigned*)d_ws + 201584;        // [NBLK*NB]  @201584 (x4B /16 ok)
    unsigned* packed = histg + (size_t)NBLK * NB;       // [E]        @601968 (x4B /16 ok)
    unsigned* tA1    = packed;                          // overlay: [N*4] u32 (16B aligned)
    unsigned* tB1    = packed + (size_t)N_NODES * 4;    // [N]
    unsigned* ecol   = packed + N_EDGES;                // [E]
    unsigned* tA0    = ecol + N_EDGES;                  // [N*4] (offset 5601968*4B, /16 ok)
    unsigned* tB0    = tA0 + (size_t)N_NODES * 4;       // [N]
    float* pooled    = (float*)(tB0 + N_NODES);         // [5][G][10]
    size_t needed = (size_t)((char*)(pooled + 5 * NGRAPH * DIM) - (char*)d_ws);
    if (needed > ws_size) return;  // loud failure (output stays zero)

    const int TB = 256;
    int nblocks = (N_NODES + TB - 1) / TB;
    int gblocks = (NGRAPH + TB - 1) / TB;

    hipMemsetAsync(tot, 0, NB * sizeof(unsigned), stream);
    hipMemsetAsync(pooled, 0, (size_t)5 * NGRAPH * DIM * sizeof(float), stream);

    // ---- build per-node CSR: hist(+totals) -> scan totals -> per-bucket block scan -> scatter -> node sort ----
    khist<<<NBLK, STB, 0, stream>>>(dst, histg, tot);
    kscan_tot<<<1, 1024, 0, stream>>>(tot, bstart);
    kscan_wb<<<NB, STB, 0, stream>>>(histg, bstart);
    kscatter<<<NBLK, STB, 0, stream>>>(src, dst, histg, packed);
    node_sort<<<NB, BNODES, 0, stream>>>(packed, bstart, ecol, rowstart);

    // ---- layer 1 (pre-applied w1) ----
    xform_kernel<<<nblocks, TB, 0, stream>>>(x, w1_1, tA0, tB0);
    gin_gatherE<true><<<N_NODES / 16, TB, 0, stream>>>(
        (const uint4*)tA0, tB0, rowstart, ecol,
        nullptr, b1_1, w2_1, b2_1, batch, tA1, tB1, pooled);

    // ---- layers 2..5 (ping-pong split tables) ----
    unsigned *iA = tA1, *iB = tB1, *oA = tA0, *oB = tB0;
    for (int l = 0; l < 4; l++) {
        gin_gatherE<false><<<N_NODES / 16, TB, 0, stream>>>(
            (const uint4*)iA, iB, rowstart, ecol,
            ws1 + (size_t)l * DIM * DIM, bs1 + (size_t)l * DIM,
            ws2 + (size_t)l * DIM * DIM, bs2 + (size_t)l * DIM,
            batch, oA, oB, pooled + (size_t)(l + 1) * NGRAPH * DIM);
        unsigned* t;
        t = iA; iA = oA; oA = t;
        t = iB; iB = oB; oB = t;
    }

    // ---- readout ----
    final_kernel<<<gblocks, TB, 0, stream>>>(pooled, batch, lw, out);
}

// Round 14
// 521.637 us; speedup vs baseline: 1.2067x; 1.2067x over previous
//
#include <hip/hip_runtime.h>
#include <math.h>

#define N_NODES 200000
#define N_EDGES 5000000
#define NFEAT 16
#define DIM 10
#define NGRAPH 1000
#define BSH 8            // 256 nodes per dst bucket
#define BNODES 256
#define NB ((N_NODES + BNODES - 1) / BNODES)   // 782
#define NBLK 512         // hist/scatter blocks
#define STB 512          // hist/scatter block size

// split bf16 tables: tA[i] = uint4 (dims 0..7, 16B aligned), tB[i] = u32 (dims 8..9)
// total 20B/node -> 4.0MB, per-XCD-L2-fit; the 16B part loads as ONE dwordx4.

// pack two f32 -> two bf16 (RNE) in one u32
__device__ __forceinline__ unsigned pkbf(float a, float b) {
    unsigned ua = __float_as_uint(a), ub = __float_as_uint(b);
    ua = (ua + 0x7fffu + ((ua >> 16) & 1u)) >> 16;
    ub = (ub + 0x7fffu + ((ub >> 16) & 1u)) >> 16;
    return ua | (ub << 16);
}
__device__ __forceinline__ float uplo(unsigned u) { return __uint_as_float(u << 16); }
__device__ __forceinline__ float uphi(unsigned u) { return __uint_as_float(u & 0xffff0000u); }

// ---------- pass 1: per-block bucket histogram + global bucket totals ----------
__global__ void __launch_bounds__(STB)
khist(const int* __restrict__ dst, unsigned* __restrict__ histg,
      unsigned* __restrict__ tot) {
    __shared__ int h[NB];
    for (int t = threadIdx.x; t < NB; t += STB) h[t] = 0;
    __syncthreads();
    int per = (N_EDGES + NBLK - 1) / NBLK;
    int e0 = blockIdx.x * per;
    int e1 = e0 + per; if (e1 > N_EDGES) e1 = N_EDGES;
    int e = e0 + threadIdx.x;
    for (; e + 7 * STB < e1; e += 8 * STB) {
        int d[8];
#pragma unroll
        for (int k = 0; k < 8; ++k) d[k] = __builtin_nontemporal_load(&dst[e + k * STB]);
#pragma unroll
        for (int k = 0; k < 8; ++k) atomicAdd(&h[d[k] >> BSH], 1);
    }
    for (; e < e1; e += STB)
        atomicAdd(&h[__builtin_nontemporal_load(&dst[e]) >> BSH], 1);
    __syncthreads();
    for (int t = threadIdx.x; t < NB; t += STB) {
        int c = h[t];
        histg[(size_t)blockIdx.x * NB + t] = c;
        if (c) atomicAdd(&tot[t], (unsigned)c);
    }
}

// ---------- pass 2a: exclusive scan of 782 bucket totals -> bstart ----------
__global__ void __launch_bounds__(1024)
kscan_tot(const unsigned* __restrict__ tot, int* __restrict__ bstart) {
    __shared__ int s[NB];
    int t = threadIdx.x;
    if (t < NB) s[t] = tot[t];
    __syncthreads();
    if (t == 0) {
        int acc = 0;
        for (int i = 0; i < NB; ++i) { int c = s[i]; s[i] = acc; acc += c; }
    }
    __syncthreads();
    if (t < NB) bstart[t] = s[t];
    if (t == 0) bstart[NB] = N_EDGES;
}

// ---------- pass 2b: per-bucket block-scan of per-block counts -> write bases ----------
__global__ void __launch_bounds__(STB)
kscan_wb(unsigned* __restrict__ histg, const int* __restrict__ bstart) {
    int t = blockIdx.x;           // bucket
    int tid = threadIdx.x;        // source block
    int lane = tid & 63, wv = tid >> 6;
    unsigned v = histg[(size_t)tid * NB + t];
    unsigned orig = v;
    // inclusive wave scan
#pragma unroll
    for (int m = 1; m < 64; m <<= 1) {
        unsigned u = __shfl(v, lane - m, 64);
        if (lane >= m) v += u;
    }
    __shared__ unsigned wtot[8];
    __shared__ unsigned wbase[8];
    if (lane == 63) wtot[wv] = v;
    __syncthreads();
    if (tid == 0) {
        unsigned acc = 0;
        for (int w = 0; w < 8; ++w) { wbase[w] = acc; acc += wtot[w]; }
    }
    __syncthreads();
    unsigned excl = v - orig + wbase[wv];
    histg[(size_t)tid * NB + t] = (unsigned)bstart[t] + excl;
}

// ---------- pass 3: single-pass scatter from precomputed bases ----------
// NOTE: packed[r] is a PLAIN store — scattered 4B writes rely on L2 write
// coalescing; nt-store here doubled WRITE_SIZE and kscatter time (R13 lesson).
__global__ void __launch_bounds__(STB)
kscatter(const int* __restrict__ src, const int* __restrict__ dst,
         const unsigned* __restrict__ histg, unsigned* __restrict__ packed) {
    __shared__ int wp[NB];
    for (int t = threadIdx.x; t < NB; t += STB)
        wp[t] = histg[(size_t)blockIdx.x * NB + t];
    __syncthreads();
    int per = (N_EDGES + NBLK - 1) / NBLK;
    int e0 = blockIdx.x * per;
    int e1 = e0 + per; if (e1 > N_EDGES) e1 = N_EDGES;
    int e = e0 + threadIdx.x;
    for (; e + 7 * STB < e1; e += 8 * STB) {
        int d[8], s[8];
#pragma unroll
        for (int k = 0; k < 8; ++k) {
            d[k] = __builtin_nontemporal_load(&dst[e + k * STB]);
            s[k] = __builtin_nontemporal_load(&src[e + k * STB]);
        }
#pragma unroll
        for (int k = 0; k < 8; ++k) {
            int r = atomicAdd(&wp[d[k] >> BSH], 1);
            packed[r] = ((unsigned)s[k] << BSH) | (unsigned)(d[k] & (BNODES - 1));
        }
    }
    for (; e < e1; e += STB) {
        int dv = __builtin_nontemporal_load(&dst[e]);
        int sv = __builtin_nontemporal_load(&src[e]);
        int r = atomicAdd(&wp[dv >> BSH], 1);
        packed[r] = ((unsigned)sv << BSH) | (unsigned)(dv & (BNODES - 1));
    }
}

// ---------- pass 4: per-bucket counting sort by dstLocal -> per-node CSR ----------
__global__ void __launch_bounds__(BNODES)
node_sort(const unsigned* __restrict__ pin, const int* __restrict__ bstart,
          unsigned* __restrict__ ecol, int* __restrict__ rowstart) {
    __shared__ int cnt[BNODES];
    __shared__ int cur[BNODES];
    int b = blockIdx.x;
    int e0 = bstart[b], e1 = bstart[b + 1];
    int tid = threadIdx.x;
    cnt[tid] = 0;
    __syncthreads();
    int e = e0 + tid;
    for (; e + 7 * BNODES < e1; e += 8 * BNODES) {
        unsigned p[8];
#pragma unroll
        for (int k = 0; k < 8; ++k) p[k] = __builtin_nontemporal_load(&pin[e + k * BNODES]);
#pragma unroll
        for (int k = 0; k < 8; ++k) atomicAdd(&cnt[p[k] & (BNODES - 1)], 1);
    }
    for (; e < e1; e += BNODES)
        atomicAdd(&cnt[__builtin_nontemporal_load(&pin[e]) & (BNODES - 1)], 1);
    __syncthreads();
    if (tid == 0) {
        int acc = 0;
        for (int t = 0; t < BNODES; ++t) { int c = cnt[t]; cur[t] = acc; acc += c; }
    }
    __syncthreads();
    int n0 = b << BSH;
    if (n0 + tid < N_NODES) rowstart[n0 + tid] = e0 + cur[tid];
    if (b == 0 && tid == 0) rowstart[N_NODES] = N_EDGES;
    e = e0 + tid;
    for (; e + 3 * BNODES < e1; e += 4 * BNODES) {
        unsigned p[4];
#pragma unroll
        for (int k = 0; k < 4; ++k) p[k] = __builtin_nontemporal_load(&pin[e + k * BNODES]);
#pragma unroll
        for (int k = 0; k < 4; ++k) {
            int slot = atomicAdd(&cur[p[k] & (BNODES - 1)], 1);
            ecol[e0 + slot] = p[k] >> BSH;
        }
    }
    for (; e < e1; e += BNODES) {
        unsigned p = __builtin_nontemporal_load(&pin[e]);
        int slot = atomicAdd(&cur[p & (BNODES - 1)], 1);
        ecol[e0 + slot] = p >> BSH;
    }
}

// ---------- y = x @ w1_1 -> split bf16 tables ----------
__global__ void xform_kernel(const float* __restrict__ x,
                             const float* __restrict__ w1,   // [16][10]
                             unsigned* __restrict__ tA,      // [N*4] u32 (16B-aligned rows)
                             unsigned* __restrict__ tB) {    // [N] u32
    int i = blockIdx.x * blockDim.x + threadIdx.x;
    if (i >= N_NODES) return;
    float xi[NFEAT];
    const float4* xr = reinterpret_cast<const float4*>(x + (size_t)i * NFEAT);
#pragma unroll
    for (int q = 0; q < 4; q++) {
        float4 v = xr[q];
        xi[q*4+0] = v.x; xi[q*4+1] = v.y; xi[q*4+2] = v.z; xi[q*4+3] = v.w;
    }
    float o[DIM];
#pragma unroll
    for (int j = 0; j < DIM; j++) {
        float s = 0.f;
#pragma unroll
        for (int f = 0; f < NFEAT; f++) s += xi[f] * w1[f * DIM + j];
        o[j] = s;
    }
#pragma unroll
    for (int k = 0; k < 4; ++k)
        __builtin_nontemporal_store(pkbf(o[2*k], o[2*k+1]), &tA[(size_t)i * 4 + k]);
    __builtin_nontemporal_store(pkbf(o[8], o[9]), &tB[i]);
}

// ---------- edge-owner gather + MLP + pool, split-table loads ----------
template <bool FIRST>
__global__ void __launch_bounds__(256, 8)
gin_gatherE(const uint4* __restrict__ tA, const unsigned* __restrict__ tB,
            const int* __restrict__ rowstart,
            const unsigned* __restrict__ ecol,
            const float* __restrict__ w1, const float* __restrict__ b1,
            const float* __restrict__ w2, const float* __restrict__ b2,
            const int* __restrict__ batch,
            unsigned* __restrict__ oA, unsigned* __restrict__ oB,
            float* __restrict__ pooled) {
    __shared__ float hp[16][DIM];
    __shared__ int gid[16];
    int tid = threadIdx.x;
    int grp = tid >> 4;
    int j = tid & 15;
    int lane = tid & 63;
    int base = lane & 48;
    int i = blockIdx.x * 16 + grp;

    int r0 = rowstart[i];
    int r1 = rowstart[i + 1];

    float a[DIM];
#pragma unroll
    for (int d = 0; d < DIM; ++d) a[d] = 0.f;

    int idx = r0 + j;
    for (; idx + 16 < r1; idx += 32) {
        unsigned sA = __builtin_nontemporal_load(&ecol[idx]);
        unsigned sB = __builtin_nontemporal_load(&ecol[idx + 16]);
        uint4 A0 = tA[sA]; unsigned B0 = tB[sA];
        uint4 A1 = tA[sB]; unsigned B1 = tB[sB];
        a[0] += uplo(A0.x) + uplo(A1.x); a[1] += uphi(A0.x) + uphi(A1.x);
        a[2] += uplo(A0.y) + uplo(A1.y); a[3] += uphi(A0.y) + uphi(A1.y);
        a[4] += uplo(A0.z) + uplo(A1.z); a[5] += uphi(A0.z) + uphi(A1.z);
        a[6] += uplo(A0.w) + uplo(A1.w); a[7] += uphi(A0.w) + uphi(A1.w);
        a[8] += uplo(B0)   + uplo(B1);   a[9] += uphi(B0)   + uphi(B1);
    }
    if (idx < r1) {
        unsigned sA = __builtin_nontemporal_load(&ecol[idx]);
        uint4 A0 = tA[sA]; unsigned B0 = tB[sA];
        a[0] += uplo(A0.x); a[1] += uphi(A0.x);
        a[2] += uplo(A0.y); a[3] += uphi(A0.y);
        a[4] += uplo(A0.z); a[5] += uphi(A0.z);
        a[6] += uplo(A0.w); a[7] += uphi(A0.w);
        a[8] += uplo(B0);   a[9] += uphi(B0);
    }

    // butterfly reduce across the 16-lane group
#pragma unroll
    for (int m = 1; m <= 8; m <<= 1) {
#pragma unroll
        for (int d = 0; d < DIM; ++d) a[d] += __shfl_xor(a[d], m, 64);
    }

    // own row (group-uniform -> broadcast)
    uint4 Ai = tA[i]; unsigned Bi = tB[i];
    float z[DIM];
    z[0] = uplo(Ai.x) + a[0]; z[1] = uphi(Ai.x) + a[1];
    z[2] = uplo(Ai.y) + a[2]; z[3] = uphi(Ai.y) + a[3];
    z[4] = uplo(Ai.z) + a[4]; z[5] = uphi(Ai.z) + a[5];
    z[6] = uplo(Ai.w) + a[6]; z[7] = uphi(Ai.w) + a[7];
    z[8] = uplo(Bi)   + a[8]; z[9] = uphi(Bi)   + a[9];

    float t1v = 0.f;
    if (FIRST) {
        if (j < DIM) {
            float s1 = z[j] + b1[j];
            t1v = s1 > 0.f ? s1 : 0.f;
        }
    } else {
        if (j < DIM) {
            float s1 = b1[j];
#pragma unroll
            for (int f = 0; f < DIM; ++f) s1 += z[f] * w1[f * DIM + j];
            t1v = s1 > 0.f ? s1 : 0.f;
        }
    }
    float s2 = (j < DIM) ? b2[j] : 0.f;
#pragma unroll
    for (int f = 0; f < DIM; ++f) {
        float tf = __shfl(t1v, base + f, 64);
        if (j < DIM) s2 += tf * w2[f * DIM + j];
    }
    float hv = s2 > 0.f ? s2 : 0.f;

    // even lanes j<10 pack (hv_j, hv_{j+1}); j<8 -> word j/2 of oA[i], j==8 -> oB[i]
    float hnext = __shfl(hv, base + ((j + 1) & 15), 64);
    if (j < DIM && !(j & 1)) {
        unsigned wword = pkbf(hv, hnext);
        if (j < 8) __builtin_nontemporal_store(wword, &oA[(size_t)i * 4 + (j >> 1)]);
        else       __builtin_nontemporal_store(wword, &oB[i]);
    }

    if (j < DIM) hp[grp][j] = hv;
    if (j == 0) gid[grp] = batch[i];
    __syncthreads();

    if (tid < DIM) {
        int cg = gid[0];
        float s = hp[0][tid];
        for (int n = 1; n < 16; ++n) {
            int g = gid[n];
            float v = hp[n][tid];
            if (g == cg) s += v;
            else { atomicAdd(&pooled[cg * DIM + tid], s); cg = g; s = v; }
        }
        atomicAdd(&pooled[cg * DIM + tid], s);
    }
}

// ---------- readout ----------
__global__ void final_kernel(const float* __restrict__ pooled,  // [5][G][10]
                             const int* __restrict__ batch,
                             const float* __restrict__ lw,      // [5][10]
                             float* __restrict__ out) {
    int g = blockIdx.x * blockDim.x + threadIdx.x;
    if (g >= NGRAPH) return;
    int lo = 0, hi = N_NODES;
    while (lo < hi) { int m = (lo + hi) >> 1; if (batch[m] < g) lo = m + 1; else hi = m; }
    int a = lo;
    hi = N_NODES;
    while (lo < hi) { int m = (lo + hi) >> 1; if (batch[m] < g + 1) lo = m + 1; else hi = m; }
    float c = (float)(lo - a);
    float inv = 1.0f / (c > 1.f ? c : 1.f);
    float s = 0.f;
#pragma unroll
    for (int l = 0; l < 5; l++) {
        float d = 0.f;
#pragma unroll
        for (int j = 0; j < DIM; j++)
            d += pooled[(size_t)l * NGRAPH * DIM + (size_t)g * DIM + j] * lw[l * DIM + j];
        s += d * inv;
    }
    out[g] = 1.0f / (1.0f + expf(-s));
}

extern "C" void kernel_launch(void* const* d_in, const int* in_sizes, int n_in,
                              void* d_out, int out_size, void* d_ws, size_t ws_size,
                              hipStream_t stream) {
    const float* x    = (const float*)d_in[0];
    const int*   ei   = (const int*)d_in[1];
    const int*   batch= (const int*)d_in[2];
    const float* w1_1 = (const float*)d_in[3];
    const float* b1_1 = (const float*)d_in[4];
    const float* w2_1 = (const float*)d_in[5];
    const float* b2_1 = (const float*)d_in[6];
    const float* ws1  = (const float*)d_in[7];   // [4][10][10]
    const float* bs1  = (const float*)d_in[8];   // [4][10]
    const float* ws2  = (const float*)d_in[9];   // [4][10][10]
    const float* bs2  = (const float*)d_in[10];  // [4][10]
    const float* lw   = (const float*)d_in[11];  // [5][10]
    float* out = (float*)d_out;

    const int* src = ei;
    const int* dst = ei + N_EDGES;

    // ---- workspace layout (u32 units; 16B-aligned table sections) ----
    int* bstart      = (int*)d_ws;                      // [NB+1]     @0
    unsigned* tot    = (unsigned*)d_ws + 784;           // [NB]       @784
    int* rowstart    = (int*)d_ws + 1568;               // [N+1]      @1568
    unsigned* histg  = (unsigned*)d_ws + 201584;        // [NBLK*NB]  @201584 (x4B /16 ok)
    unsigned* packed = histg + (size_t)NBLK * NB;       // [E]        @601968 (x4B /16 ok)
    unsigned* tA1    = packed;                          // overlay: [N*4] u32 (16B aligned)
    unsigned* tB1    = packed + (size_t)N_NODES * 4;    // [N]
    unsigned* ecol   = packed + N_EDGES;                // [E]
    unsigned* tA0    = ecol + N_EDGES;                  // [N*4] (16B aligned)
    unsigned* tB0    = tA0 + (size_t)N_NODES * 4;       // [N]
    float* pooled    = (float*)(tB0 + N_NODES);         // [5][G][10]
    size_t needed = (size_t)((char*)(pooled + 5 * NGRAPH * DIM) - (char*)d_ws);
    if (needed > ws_size) return;  // loud failure (output stays zero)

    const int TB = 256;
    int nblocks = (N_NODES + TB - 1) / TB;
    int gblocks = (NGRAPH + TB - 1) / TB;

    hipMemsetAsync(tot, 0, NB * sizeof(unsigned), stream);
    hipMemsetAsync(pooled, 0, (size_t)5 * NGRAPH * DIM * sizeof(float), stream);

    // ---- build per-node CSR ----
    khist<<<NBLK, STB, 0, stream>>>(dst, histg, tot);
    kscan_tot<<<1, 1024, 0, stream>>>(tot, bstart);
    kscan_wb<<<NB, STB, 0, stream>>>(histg, bstart);
    kscatter<<<NBLK, STB, 0, stream>>>(src, dst, histg, packed);
    node_sort<<<NB, BNODES, 0, stream>>>(packed, bstart, ecol, rowstart);

    // ---- layer 1 (pre-applied w1) ----
    xform_kernel<<<nblocks, TB, 0, stream>>>(x, w1_1, tA0, tB0);
    gin_gatherE<true><<<N_NODES / 16, TB, 0, stream>>>(
        (const uint4*)tA0, tB0, rowstart, ecol,
        nullptr, b1_1, w2_1, b2_1, batch, tA1, tB1, pooled);

    // ---- layers 2..5 (ping-pong split tables) ----
    unsigned *iA = tA1, *iB = tB1, *oA = tA0, *oB = tB0;
    for (int l = 0; l < 4; l++) {
        gin_gatherE<false><<<N_NODES / 16, TB, 0, stream>>>(
            (const uint4*)iA, iB, rowstart, ecol,
            ws1 + (size_t)l * DIM * DIM, bs1 + (size_t)l * DIM,
            ws2 + (size_t)l * DIM * DIM, bs2 + (size_t)l * DIM,
            batch, oA, oB, pooled + (size_t)(l + 1) * NGRAPH * DIM);
        unsigned* t;
        t = iA; iA = oA; oA = t;
        t = iB; iB = oB; oB = t;
    }

    // ---- readout ----
    final_kernel<<<gblocks, TB, 0, stream>>>(pooled, batch, lw, out);
}

// Round 15
// 465.022 us; speedup vs baseline: 1.3536x; 1.1217x over previous
//
#include <hip/hip_runtime.h>
#include <math.h>

#define N_NODES 200000
#define N_EDGES 5000000
#define NFEAT 16
#define DIM 10
#define NGRAPH 1000
#define BSH 8            // 256 nodes per dst bucket
#define BNODES 256
#define NB ((N_NODES + BNODES - 1) / BNODES)   // 782
#define NBLK 512         // hist/scatter blocks
#define STB 512          // hist/scatter block size
#define RSTRIDE 5        // packed 20B rows -> 4.0MB table, L2-fit, 1.25 lines/edge

// pack two f32 -> two bf16 (RNE) in one u32
__device__ __forceinline__ unsigned pkbf(float a, float b) {
    unsigned ua = __float_as_uint(a), ub = __float_as_uint(b);
    ua = (ua + 0x7fffu + ((ua >> 16) & 1u)) >> 16;
    ub = (ub + 0x7fffu + ((ub >> 16) & 1u)) >> 16;
    return ua | (ub << 16);
}
__device__ __forceinline__ float uplo(unsigned u) { return __uint_as_float(u << 16); }
__device__ __forceinline__ float uphi(unsigned u) { return __uint_as_float(u & 0xffff0000u); }

// ---------- pass 1: per-block bucket histogram + global bucket totals ----------
__global__ void __launch_bounds__(STB)
khist(const int* __restrict__ dst, unsigned* __restrict__ histg,
      unsigned* __restrict__ tot) {
    __shared__ int h[NB];
    for (int t = threadIdx.x; t < NB; t += STB) h[t] = 0;
    __syncthreads();
    int per = (N_EDGES + NBLK - 1) / NBLK;
    int e0 = blockIdx.x * per;
    int e1 = e0 + per; if (e1 > N_EDGES) e1 = N_EDGES;
    int e = e0 + threadIdx.x;
    for (; e + 7 * STB < e1; e += 8 * STB) {
        int d[8];
#pragma unroll
        for (int k = 0; k < 8; ++k) d[k] = __builtin_nontemporal_load(&dst[e + k * STB]);
#pragma unroll
        for (int k = 0; k < 8; ++k) atomicAdd(&h[d[k] >> BSH], 1);
    }
    for (; e < e1; e += STB)
        atomicAdd(&h[__builtin_nontemporal_load(&dst[e]) >> BSH], 1);
    __syncthreads();
    for (int t = threadIdx.x; t < NB; t += STB) {
        int c = h[t];
        histg[(size_t)blockIdx.x * NB + t] = c;
        if (c) atomicAdd(&tot[t], (unsigned)c);
    }
}

// ---------- pass 2a: exclusive scan of 782 bucket totals -> bstart ----------
__global__ void __launch_bounds__(1024)
kscan_tot(const unsigned* __restrict__ tot, int* __restrict__ bstart) {
    __shared__ int s[NB];
    int t = threadIdx.x;
    if (t < NB) s[t] = tot[t];
    __syncthreads();
    if (t == 0) {
        int acc = 0;
        for (int i = 0; i < NB; ++i) { int c = s[i]; s[i] = acc; acc += c; }
    }
    __syncthreads();
    if (t < NB) bstart[t] = s[t];
    if (t == 0) bstart[NB] = N_EDGES;
}

// ---------- pass 2b: per-bucket block-scan of per-block counts -> write bases ----------
__global__ void __launch_bounds__(STB)
kscan_wb(unsigned* __restrict__ histg, const int* __restrict__ bstart) {
    int t = blockIdx.x;           // bucket
    int tid = threadIdx.x;        // source block
    int lane = tid & 63, wv = tid >> 6;
    unsigned v = histg[(size_t)tid * NB + t];
    unsigned orig = v;
#pragma unroll
    for (int m = 1; m < 64; m <<= 1) {
        unsigned u = __shfl(v, lane - m, 64);
        if (lane >= m) v += u;
    }
    __shared__ unsigned wtot[8];
    __shared__ unsigned wbase[8];
    if (lane == 63) wtot[wv] = v;
    __syncthreads();
    if (tid == 0) {
        unsigned acc = 0;
        for (int w = 0; w < 8; ++w) { wbase[w] = acc; acc += wtot[w]; }
    }
    __syncthreads();
    unsigned excl = v - orig + wbase[wv];
    histg[(size_t)tid * NB + t] = (unsigned)bstart[t] + excl;
}

// ---------- pass 3: single-pass scatter (PLAIN scattered stores — R13 lesson) ----------
__global__ void __launch_bounds__(STB)
kscatter(const int* __restrict__ src, const int* __restrict__ dst,
         const unsigned* __restrict__ histg, unsigned* __restrict__ packed) {
    __shared__ int wp[NB];
    for (int t = threadIdx.x; t < NB; t += STB)
        wp[t] = histg[(size_t)blockIdx.x * NB + t];
    __syncthreads();
    int per = (N_EDGES + NBLK - 1) / NBLK;
    int e0 = blockIdx.x * per;
    int e1 = e0 + per; if (e1 > N_EDGES) e1 = N_EDGES;
    int e = e0 + threadIdx.x;
    for (; e + 7 * STB < e1; e += 8 * STB) {
        int d[8], s[8];
#pragma unroll
        for (int k = 0; k < 8; ++k) {
            d[k] = __builtin_nontemporal_load(&dst[e + k * STB]);
            s[k] = __builtin_nontemporal_load(&src[e + k * STB]);
        }
#pragma unroll
        for (int k = 0; k < 8; ++k) {
            int r = atomicAdd(&wp[d[k] >> BSH], 1);
            packed[r] = ((unsigned)s[k] << BSH) | (unsigned)(d[k] & (BNODES - 1));
        }
    }
    for (; e < e1; e += STB) {
        int dv = __builtin_nontemporal_load(&dst[e]);
        int sv = __builtin_nontemporal_load(&src[e]);
        int r = atomicAdd(&wp[dv >> BSH], 1);
        packed[r] = ((unsigned)sv << BSH) | (unsigned)(dv & (BNODES - 1));
    }
}

// ---------- pass 4: per-bucket counting sort by dstLocal -> per-node CSR ----------
__global__ void __launch_bounds__(BNODES)
node_sort(const unsigned* __restrict__ pin, const int* __restrict__ bstart,
          unsigned* __restrict__ ecol, int* __restrict__ rowstart) {
    __shared__ int cnt[BNODES];
    __shared__ int cur[BNODES];
    int b = blockIdx.x;
    int e0 = bstart[b], e1 = bstart[b + 1];
    int tid = threadIdx.x;
    cnt[tid] = 0;
    __syncthreads();
    int e = e0 + tid;
    for (; e + 7 * BNODES < e1; e += 8 * BNODES) {
        unsigned p[8];
#pragma unroll
        for (int k = 0; k < 8; ++k) p[k] = __builtin_nontemporal_load(&pin[e + k * BNODES]);
#pragma unroll
        for (int k = 0; k < 8; ++k) atomicAdd(&cnt[p[k] & (BNODES - 1)], 1);
    }
    for (; e < e1; e += BNODES)
        atomicAdd(&cnt[__builtin_nontemporal_load(&pin[e]) & (BNODES - 1)], 1);
    __syncthreads();
    if (tid == 0) {
        int acc = 0;
        for (int t = 0; t < BNODES; ++t) { int c = cnt[t]; cur[t] = acc; acc += c; }
    }
    __syncthreads();
    int n0 = b << BSH;
    if (n0 + tid < N_NODES) rowstart[n0 + tid] = e0 + cur[tid];
    if (b == 0 && tid == 0) rowstart[N_NODES] = N_EDGES;
    e = e0 + tid;
    for (; e + 3 * BNODES < e1; e += 4 * BNODES) {
        unsigned p[4];
#pragma unroll
        for (int k = 0; k < 4; ++k) p[k] = __builtin_nontemporal_load(&pin[e + k * BNODES]);
#pragma unroll
        for (int k = 0; k < 4; ++k) {
            int slot = atomicAdd(&cur[p[k] & (BNODES - 1)], 1);
            ecol[e0 + slot] = p[k] >> BSH;
        }
    }
    for (; e < e1; e += BNODES) {
        unsigned p = __builtin_nontemporal_load(&pin[e]);
        int slot = atomicAdd(&cur[p & (BNODES - 1)], 1);
        ecol[e0 + slot] = p >> BSH;
    }
}

// ---------- y = x @ w1_1 -> packed bf16 rows, 20B stride ----------
__global__ void xform_kernel(const float* __restrict__ x,
                             const float* __restrict__ w1,   // [16][10]
                             unsigned* __restrict__ tout) {  // [N][5] u32
    int i = blockIdx.x * blockDim.x + threadIdx.x;
    if (i >= N_NODES) return;
    float xi[NFEAT];
    const float4* xr = reinterpret_cast<const float4*>(x + (size_t)i * NFEAT);
#pragma unroll
    for (int q = 0; q < 4; q++) {
        float4 v = xr[q];
        xi[q*4+0] = v.x; xi[q*4+1] = v.y; xi[q*4+2] = v.z; xi[q*4+3] = v.w;
    }
    float o[DIM];
#pragma unroll
    for (int j = 0; j < DIM; j++) {
        float s = 0.f;
#pragma unroll
        for (int f = 0; f < NFEAT; f++) s += xi[f] * w1[f * DIM + j];
        o[j] = s;
    }
#pragma unroll
    for (int k = 0; k < 5; k++)
        __builtin_nontemporal_store(pkbf(o[2*k], o[2*k+1]),
                                    &tout[(size_t)RSTRIDE * i + k]);
}

// ---------- edge-owner gather + MLP + pool, packed-row loads (R11 winner) ----------
// Each lane owns one edge: 5 consecutive dword loads of one 20B row (1.25
// lines/edge; L1 absorbs same-line redundancy). Unroll-2 for ILP.
template <bool FIRST>
__global__ void __launch_bounds__(256, 8)
gin_gatherE(const unsigned* __restrict__ tin,     // [N][5] u32 bf16 rows
            const int* __restrict__ rowstart,
            const unsigned* __restrict__ ecol,
            const float* __restrict__ w1, const float* __restrict__ b1,
            const float* __restrict__ w2, const float* __restrict__ b2,
            const int* __restrict__ batch,
            unsigned* __restrict__ tout,
            float* __restrict__ pooled) {
    __shared__ float hp[16][DIM];
    __shared__ int gid[16];
    int tid = threadIdx.x;
    int grp = tid >> 4;
    int j = tid & 15;
    int lane = tid & 63;
    int base = lane & 48;
    int i = blockIdx.x * 16 + grp;

    int r0 = rowstart[i];
    int r1 = rowstart[i + 1];

    float a[DIM];
#pragma unroll
    for (int d = 0; d < DIM; ++d) a[d] = 0.f;

    int idx = r0 + j;
    for (; idx + 16 < r1; idx += 32) {
        unsigned sA = __builtin_nontemporal_load(&ecol[idx]);
        unsigned sB = __builtin_nontemporal_load(&ecol[idx + 16]);
        const unsigned* rA = tin + (size_t)sA * RSTRIDE;
        const unsigned* rB = tin + (size_t)sB * RSTRIDE;
        unsigned wA[5], wB[5];
#pragma unroll
        for (int k = 0; k < 5; ++k) wA[k] = rA[k];
#pragma unroll
        for (int k = 0; k < 5; ++k) wB[k] = rB[k];
#pragma unroll
        for (int k = 0; k < 5; ++k) {
            a[2*k]   += uplo(wA[k]) + uplo(wB[k]);
            a[2*k+1] += uphi(wA[k]) + uphi(wB[k]);
        }
    }
    if (idx < r1) {
        unsigned sA = __builtin_nontemporal_load(&ecol[idx]);
        const unsigned* rA = tin + (size_t)sA * RSTRIDE;
        unsigned wA[5];
#pragma unroll
        for (int k = 0; k < 5; ++k) wA[k] = rA[k];
#pragma unroll
        for (int k = 0; k < 5; ++k) {
            a[2*k]   += uplo(wA[k]);
            a[2*k+1] += uphi(wA[k]);
        }
    }

    // butterfly reduce across the 16-lane group
#pragma unroll
    for (int m = 1; m <= 8; m <<= 1) {
#pragma unroll
        for (int d = 0; d < DIM; ++d) a[d] += __shfl_xor(a[d], m, 64);
    }

    // own row (group-uniform -> broadcast); full z per lane
    const unsigned* ri = tin + (size_t)i * RSTRIDE;
    float z[DIM];
#pragma unroll
    for (int k = 0; k < 5; ++k) {
        unsigned w = ri[k];
        z[2*k]   = uplo(w) + a[2*k];
        z[2*k+1] = uphi(w) + a[2*k+1];
    }

    float t1v = 0.f;
    if (FIRST) {
        if (j < DIM) {
            float s1 = z[j] + b1[j];
            t1v = s1 > 0.f ? s1 : 0.f;
        }
    } else {
        if (j < DIM) {
            float s1 = b1[j];
#pragma unroll
            for (int f = 0; f < DIM; ++f) s1 += z[f] * w1[f * DIM + j];
            t1v = s1 > 0.f ? s1 : 0.f;
        }
    }
    float s2 = (j < DIM) ? b2[j] : 0.f;
#pragma unroll
    for (int f = 0; f < DIM; ++f) {
        float tf = __shfl(t1v, base + f, 64);
        if (j < DIM) s2 += tf * w2[f * DIM + j];
    }
    float hv = s2 > 0.f ? s2 : 0.f;

    float hnext = __shfl(hv, base + ((j + 1) & 15), 64);
    if (j < DIM && !(j & 1))
        __builtin_nontemporal_store(pkbf(hv, hnext), &tout[(size_t)i * RSTRIDE + (j >> 1)]);

    if (j < DIM) hp[grp][j] = hv;
    if (j == 0) gid[grp] = batch[i];
    __syncthreads();

    if (tid < DIM) {
        int cg = gid[0];
        float s = hp[0][tid];
        for (int n = 1; n < 16; ++n) {
            int g = gid[n];
            float v = hp[n][tid];
            if (g == cg) s += v;
            else { atomicAdd(&pooled[cg * DIM + tid], s); cg = g; s = v; }
        }
        atomicAdd(&pooled[cg * DIM + tid], s);
    }
}

// ---------- readout ----------
__global__ void final_kernel(const float* __restrict__ pooled,  // [5][G][10]
                             const int* __restrict__ batch,
                             const float* __restrict__ lw,      // [5][10]
                             float* __restrict__ out) {
    int g = blockIdx.x * blockDim.x + threadIdx.x;
    if (g >= NGRAPH) return;
    int lo = 0, hi = N_NODES;
    while (lo < hi) { int m = (lo + hi) >> 1; if (batch[m] < g) lo = m + 1; else hi = m; }
    int a = lo;
    hi = N_NODES;
    while (lo < hi) { int m = (lo + hi) >> 1; if (batch[m] < g + 1) lo = m + 1; else hi = m; }
    float c = (float)(lo - a);
    float inv = 1.0f / (c > 1.f ? c : 1.f);
    float s = 0.f;
#pragma unroll
    for (int l = 0; l < 5; l++) {
        float d = 0.f;
#pragma unroll
        for (int j = 0; j < DIM; j++)
            d += pooled[(size_t)l * NGRAPH * DIM + (size_t)g * DIM + j] * lw[l * DIM + j];
        s += d * inv;
    }
    out[g] = 1.0f / (1.0f + expf(-s));
}

extern "C" void kernel_launch(void* const* d_in, const int* in_sizes, int n_in,
                              void* d_out, int out_size, void* d_ws, size_t ws_size,
                              hipStream_t stream) {
    const float* x    = (const float*)d_in[0];
    const int*   ei   = (const int*)d_in[1];
    const int*   batch= (const int*)d_in[2];
    const float* w1_1 = (const float*)d_in[3];
    const float* b1_1 = (const float*)d_in[4];
    const float* w2_1 = (const float*)d_in[5];
    const float* b2_1 = (const float*)d_in[6];
    const float* ws1  = (const float*)d_in[7];   // [4][10][10]
    const float* bs1  = (const float*)d_in[8];   // [4][10]
    const float* ws2  = (const float*)d_in[9];   // [4][10][10]
    const float* bs2  = (const float*)d_in[10];  // [4][10]
    const float* lw   = (const float*)d_in[11];  // [5][10]
    float* out = (float*)d_out;

    const int* src = ei;
    const int* dst = ei + N_EDGES;

    // ---- workspace layout (u32 units) ----
    int* bstart      = (int*)d_ws;                      // [NB+1]     @0
    unsigned* tot    = (unsigned*)d_ws + 784;           // [NB]       @784
    int* rowstart    = (int*)d_ws + 1568;               // [N+1]      @1568
    unsigned* histg  = (unsigned*)d_ws + 201584;        // [NBLK*NB]  @201584
    unsigned* packed = histg + (size_t)NBLK * NB;       // [E] (dead after node_sort; reused as tA1)
    unsigned* tA1    = packed;                          // overlay: [N*5]
    unsigned* ecol   = packed + N_EDGES;                // [E]
    unsigned* tA0    = ecol + N_EDGES;                  // [N*5]
    float* pooled    = (float*)(tA0 + (size_t)N_NODES * RSTRIDE); // [5][G][10]
    size_t needed = (size_t)((char*)(pooled + 5 * NGRAPH * DIM) - (char*)d_ws);
    if (needed > ws_size) return;  // loud failure (output stays zero)

    const int TB = 256;
    int nblocks = (N_NODES + TB - 1) / TB;
    int gblocks = (NGRAPH + TB - 1) / TB;

    hipMemsetAsync(tot, 0, NB * sizeof(unsigned), stream);
    hipMemsetAsync(pooled, 0, (size_t)5 * NGRAPH * DIM * sizeof(float), stream);

    // ---- build per-node CSR ----
    khist<<<NBLK, STB, 0, stream>>>(dst, histg, tot);
    kscan_tot<<<1, 1024, 0, stream>>>(tot, bstart);
    kscan_wb<<<NB, STB, 0, stream>>>(histg, bstart);
    kscatter<<<NBLK, STB, 0, stream>>>(src, dst, histg, packed);
    node_sort<<<NB, BNODES, 0, stream>>>(packed, bstart, ecol, rowstart);

    // ---- layer 1 (pre-applied w1) ----
    xform_kernel<<<nblocks, TB, 0, stream>>>(x, w1_1, tA0);
    gin_gatherE<true><<<N_NODES / 16, TB, 0, stream>>>(tA0, rowstart, ecol,
        nullptr, b1_1, w2_1, b2_1, batch, tA1, pooled);

    // ---- layers 2..5 (ping-pong) ----
    unsigned *tin = tA1, *tout2 = tA0;
    for (int l = 0; l < 4; l++) {
        gin_gatherE<false><<<N_NODES / 16, TB, 0, stream>>>(tin, rowstart, ecol,
            ws1 + (size_t)l * DIM * DIM, bs1 + (size_t)l * DIM,
            ws2 + (size_t)l * DIM * DIM, bs2 + (size_t)l * DIM,
            batch, tout2, pooled + (size_t)(l + 1) * NGRAPH * DIM);
        unsigned* t = tin; tin = tout2; tout2 = t;
    }

    // ---- readout ----
    final_kernel<<<gblocks, TB, 0, stream>>>(pooled, batch, lw, out);
}

// Round 16
// 397.904 us; speedup vs baseline: 1.5820x; 1.1687x over previous
//
#include <hip/hip_runtime.h>
#include <math.h>

#define N_NODES 200000
#define N_EDGES 5000000
#define NFEAT 16
#define DIM 10
#define NGRAPH 1000
#define BSH 8            // 256 nodes per dst bucket
#define BNODES 256
#define NB ((N_NODES + BNODES - 1) / BNODES)   // 782
#define NBLK 512         // hist/scatter blocks
#define STB 512          // hist/scatter block size
#define CH ((N_EDGES + NBLK - 1) / NBLK)       // 9766 edges per scatter chunk
#define NSCAP 8192       // node_sort LDS stage capacity (bucket max ~6800)
#define RSTRIDE 5        // packed 20B rows -> 4.0MB table, L2-fit, 1.25 lines/edge

// pack two f32 -> two bf16 (RNE) in one u32
__device__ __forceinline__ unsigned pkbf(float a, float b) {
    unsigned ua = __float_as_uint(a), ub = __float_as_uint(b);
    ua = (ua + 0x7fffu + ((ua >> 16) & 1u)) >> 16;
    ub = (ub + 0x7fffu + ((ub >> 16) & 1u)) >> 16;
    return ua | (ub << 16);
}
__device__ __forceinline__ float uplo(unsigned u) { return __uint_as_float(u << 16); }
__device__ __forceinline__ float uphi(unsigned u) { return __uint_as_float(u & 0xffff0000u); }

// ---------- pass 1: per-block bucket histogram + global bucket totals ----------
__global__ void __launch_bounds__(STB)
khist(const int* __restrict__ dst, unsigned* __restrict__ histg,
      unsigned* __restrict__ tot) {
    __shared__ int h[NB];
    for (int t = threadIdx.x; t < NB; t += STB) h[t] = 0;
    __syncthreads();
    int e0 = blockIdx.x * CH;
    int e1 = e0 + CH; if (e1 > N_EDGES) e1 = N_EDGES;
    int e = e0 + threadIdx.x;
    for (; e + 7 * STB < e1; e += 8 * STB) {
        int d[8];
#pragma unroll
        for (int k = 0; k < 8; ++k) d[k] = __builtin_nontemporal_load(&dst[e + k * STB]);
#pragma unroll
        for (int k = 0; k < 8; ++k) atomicAdd(&h[d[k] >> BSH], 1);
    }
    for (; e < e1; e += STB)
        atomicAdd(&h[__builtin_nontemporal_load(&dst[e]) >> BSH], 1);
    __syncthreads();
    for (int t = threadIdx.x; t < NB; t += STB) {
        int c = h[t];
        histg[(size_t)blockIdx.x * NB + t] = c;   // RAW counts (kept)
        if (c) atomicAdd(&tot[t], (unsigned)c);
    }
}

// ---------- pass 2a: exclusive scan of 782 bucket totals -> bstart ----------
__global__ void __launch_bounds__(1024)
kscan_tot(const unsigned* __restrict__ tot, int* __restrict__ bstart) {
    __shared__ int s[NB];
    int t = threadIdx.x;
    if (t < NB) s[t] = tot[t];
    __syncthreads();
    if (t == 0) {
        int acc = 0;
        for (int i = 0; i < NB; ++i) { int c = s[i]; s[i] = acc; acc += c; }
    }
    __syncthreads();
    if (t < NB) bstart[t] = s[t];
    if (t == 0) bstart[NB] = N_EDGES;
}

// ---------- pass 2b: per-bucket block-scan of per-block counts -> wbaseg ----------
// histg keeps raw counts; write bases go to wbaseg (kscatter needs both).
__global__ void __launch_bounds__(STB)
kscan_wb(const unsigned* __restrict__ histg, unsigned* __restrict__ wbaseg,
         const int* __restrict__ bstart) {
    int t = blockIdx.x;           // bucket
    int tid = threadIdx.x;        // source block
    int lane = tid & 63, wv = tid >> 6;
    unsigned v = histg[(size_t)tid * NB + t];
    unsigned orig = v;
#pragma unroll
    for (int m = 1; m < 64; m <<= 1) {
        unsigned u = __shfl(v, lane - m, 64);
        if (lane >= m) v += u;
    }
    __shared__ unsigned wtot[8];
    __shared__ unsigned wbase[8];
    if (lane == 63) wtot[wv] = v;
    __syncthreads();
    if (tid == 0) {
        unsigned acc = 0;
        for (int w = 0; w < 8; ++w) { wbase[w] = acc; acc += wtot[w]; }
    }
    __syncthreads();
    unsigned excl = v - orig + wbase[wv];
    wbaseg[(size_t)tid * NB + t] = (unsigned)bstart[t] + excl;
}

// ---------- pass 3: scatter via LDS bucket-sorted stage + coalesced flush ----------
__global__ void __launch_bounds__(STB)
kscatter(const int* __restrict__ src, const int* __restrict__ dst,
         const unsigned* __restrict__ histg, const unsigned* __restrict__ wbaseg,
         unsigned* __restrict__ packed) {
    __shared__ unsigned stage[CH];
    __shared__ unsigned short bkt16[CH];
    __shared__ int cur[NB];
    __shared__ int wadj[NB];
    __shared__ int wtot[8], wbase2[8];
    int tid = threadIdx.x;
    int blk = blockIdx.x;
    int e0 = blk * CH;
    int e1 = e0 + CH; if (e1 > N_EDGES) e1 = N_EDGES;
    int cnt = e1 - e0;

    // block-scan of this block's 782 counts (pairs over 512 threads)
    int i0 = 2 * tid, i1 = 2 * tid + 1;
    int a0 = (i0 < NB) ? (int)histg[(size_t)blk * NB + i0] : 0;
    int a1 = (i1 < NB) ? (int)histg[(size_t)blk * NB + i1] : 0;
    int s = a0 + a1;
    int lane = tid & 63, wv = tid >> 6;
    int v = s;
#pragma unroll
    for (int m = 1; m < 64; m <<= 1) {
        int u = __shfl(v, lane - m, 64);
        if (lane >= m) v += u;
    }
    if (lane == 63) wtot[wv] = v;
    __syncthreads();
    if (tid == 0) { int acc = 0; for (int w = 0; w < 8; ++w) { wbase2[w] = acc; acc += wtot[w]; } }
    __syncthreads();
    int excl = v - s + wbase2[wv];
    if (i0 < NB) { cur[i0] = excl;      wadj[i0] = (int)wbaseg[(size_t)blk * NB + i0] - excl; }
    if (i1 < NB) { cur[i1] = excl + a0; wadj[i1] = (int)wbaseg[(size_t)blk * NB + i1] - (excl + a0); }
    __syncthreads();

    // single read pass: scatter into bucket-sorted LDS stage
    int p = tid;
    for (; p + 3 * STB < cnt; p += 4 * STB) {
        int d[4], sv[4];
#pragma unroll
        for (int k = 0; k < 4; ++k) {
            d[k]  = __builtin_nontemporal_load(&dst[e0 + p + k * STB]);
            sv[k] = __builtin_nontemporal_load(&src[e0 + p + k * STB]);
        }
#pragma unroll
        for (int k = 0; k < 4; ++k) {
            int t = d[k] >> BSH;
            int pos = atomicAdd(&cur[t], 1);
            stage[pos] = ((unsigned)sv[k] << BSH) | (unsigned)(d[k] & (BNODES - 1));
            bkt16[pos] = (unsigned short)t;
        }
    }
    for (; p < cnt; p += STB) {
        int d = __builtin_nontemporal_load(&dst[e0 + p]);
        int sv = __builtin_nontemporal_load(&src[e0 + p]);
        int t = d >> BSH;
        int pos = atomicAdd(&cur[t], 1);
        stage[pos] = ((unsigned)sv << BSH) | (unsigned)(d & (BNODES - 1));
        bkt16[pos] = (unsigned short)t;
    }
    __syncthreads();

    // coalesced flush: consecutive q within a bucket -> consecutive global addr
    for (int q = tid; q < cnt; q += STB) {
        int t = bkt16[q];
        packed[wadj[t] + q] = stage[q];
    }
}

// ---------- pass 4: per-bucket counting sort (LDS stage, coalesced ecol) ----------
__global__ void __launch_bounds__(BNODES)
node_sort(const unsigned* __restrict__ pin, const int* __restrict__ bstart,
          unsigned* __restrict__ ecol, int* __restrict__ rowstart) {
    __shared__ int cnt[BNODES];
    __shared__ int cur[BNODES];
    __shared__ unsigned stage[NSCAP];
    int b = blockIdx.x;
    int e0 = bstart[b], e1 = bstart[b + 1];
    int n = e1 - e0;
    int tid = threadIdx.x;
    cnt[tid] = 0;
    __syncthreads();
    int e = e0 + tid;
    for (; e + 7 * BNODES < e1; e += 8 * BNODES) {
        unsigned p[8];
#pragma unroll
        for (int k = 0; k < 8; ++k) p[k] = __builtin_nontemporal_load(&pin[e + k * BNODES]);
#pragma unroll
        for (int k = 0; k < 8; ++k) atomicAdd(&cnt[p[k] & (BNODES - 1)], 1);
    }
    for (; e < e1; e += BNODES)
        atomicAdd(&cnt[__builtin_nontemporal_load(&pin[e]) & (BNODES - 1)], 1);
    __syncthreads();
    if (tid == 0) {
        int acc = 0;
        for (int t = 0; t < BNODES; ++t) { int c = cnt[t]; cur[t] = acc; acc += c; }
    }
    __syncthreads();
    int n0 = b << BSH;
    if (n0 + tid < N_NODES) rowstart[n0 + tid] = e0 + cur[tid];
    if (b == 0 && tid == 0) rowstart[N_NODES] = N_EDGES;
    if (n <= NSCAP) {
        e = e0 + tid;
        for (; e + 3 * BNODES < e1; e += 4 * BNODES) {
            unsigned p[4];
#pragma unroll
            for (int k = 0; k < 4; ++k) p[k] = __builtin_nontemporal_load(&pin[e + k * BNODES]);
#pragma unroll
            for (int k = 0; k < 4; ++k) {
                int slot = atomicAdd(&cur[p[k] & (BNODES - 1)], 1);
                stage[slot] = p[k] >> BSH;
            }
        }
        for (; e < e1; e += BNODES) {
            unsigned p = __builtin_nontemporal_load(&pin[e]);
            int slot = atomicAdd(&cur[p & (BNODES - 1)], 1);
            stage[slot] = p >> BSH;
        }
        __syncthreads();
        for (int q = tid; q < n; q += BNODES) ecol[e0 + q] = stage[q];
    } else {
        // fallback (bucket overflow — shouldn't happen for uniform dst)
        e = e0 + tid;
        for (; e < e1; e += BNODES) {
            unsigned p = __builtin_nontemporal_load(&pin[e]);
            int slot = atomicAdd(&cur[p & (BNODES - 1)], 1);
            ecol[e0 + slot] = p >> BSH;
        }
    }
}

// ---------- y = x @ w1_1 -> packed bf16 rows, 20B stride ----------
__global__ void xform_kernel(const float* __restrict__ x,
                             const float* __restrict__ w1,   // [16][10]
                             unsigned* __restrict__ tout) {  // [N][5] u32
    int i = blockIdx.x * blockDim.x + threadIdx.x;
    if (i >= N_NODES) return;
    float xi[NFEAT];
    const float4* xr = reinterpret_cast<const float4*>(x + (size_t)i * NFEAT);
#pragma unroll
    for (int q = 0; q < 4; q++) {
        float4 v = xr[q];
        xi[q*4+0] = v.x; xi[q*4+1] = v.y; xi[q*4+2] = v.z; xi[q*4+3] = v.w;
    }
    float o[DIM];
#pragma unroll
    for (int j = 0; j < DIM; j++) {
        float s = 0.f;
#pragma unroll
        for (int f = 0; f < NFEAT; f++) s += xi[f] * w1[f * DIM + j];
        o[j] = s;
    }
#pragma unroll
    for (int k = 0; k < 5; k++)
        __builtin_nontemporal_store(pkbf(o[2*k], o[2*k+1]),
                                    &tout[(size_t)RSTRIDE * i + k]);
}

// ---------- edge-owner gather + MLP + pool, packed-row loads ----------
template <bool FIRST>
__global__ void __launch_bounds__(256, 8)
gin_gatherE(const unsigned* __restrict__ tin,     // [N][5] u32 bf16 rows
            const int* __restrict__ rowstart,
            const unsigned* __restrict__ ecol,
            const float* __restrict__ w1, const float* __restrict__ b1,
            const float* __restrict__ w2, const float* __restrict__ b2,
            const int* __restrict__ batch,
            unsigned* __restrict__ tout,
            float* __restrict__ pooled) {
    __shared__ float hp[16][DIM];
    __shared__ int gid[16];
    int tid = threadIdx.x;
    int grp = tid >> 4;
    int j = tid & 15;
    int lane = tid & 63;
    int base = lane & 48;
    int i = blockIdx.x * 16 + grp;

    int r0 = rowstart[i];
    int r1 = rowstart[i + 1];

    float a[DIM];
#pragma unroll
    for (int d = 0; d < DIM; ++d) a[d] = 0.f;

    int idx = r0 + j;
    for (; idx + 16 < r1; idx += 32) {
        unsigned sA = __builtin_nontemporal_load(&ecol[idx]);
        unsigned sB = __builtin_nontemporal_load(&ecol[idx + 16]);
        const unsigned* rA = tin + (size_t)sA * RSTRIDE;
        const unsigned* rB = tin + (size_t)sB * RSTRIDE;
        unsigned wA[5], wB[5];
#pragma unroll
        for (int k = 0; k < 5; ++k) wA[k] = rA[k];
#pragma unroll
        for (int k = 0; k < 5; ++k) wB[k] = rB[k];
#pragma unroll
        for (int k = 0; k < 5; ++k) {
            a[2*k]   += uplo(wA[k]) + uplo(wB[k]);
            a[2*k+1] += uphi(wA[k]) + uphi(wB[k]);
        }
    }
    if (idx < r1) {
        unsigned sA = __builtin_nontemporal_load(&ecol[idx]);
        const unsigned* rA = tin + (size_t)sA * RSTRIDE;
        unsigned wA[5];
#pragma unroll
        for (int k = 0; k < 5; ++k) wA[k] = rA[k];
#pragma unroll
        for (int k = 0; k < 5; ++k) {
            a[2*k]   += uplo(wA[k]);
            a[2*k+1] += uphi(wA[k]);
        }
    }

#pragma unroll
    for (int m = 1; m <= 8; m <<= 1) {
#pragma unroll
        for (int d = 0; d < DIM; ++d) a[d] += __shfl_xor(a[d], m, 64);
    }

    const unsigned* ri = tin + (size_t)i * RSTRIDE;
    float z[DIM];
#pragma unroll
    for (int k = 0; k < 5; ++k) {
        unsigned w = ri[k];
        z[2*k]   = uplo(w) + a[2*k];
        z[2*k+1] = uphi(w) + a[2*k+1];
    }

    float t1v = 0.f;
    if (FIRST) {
        if (j < DIM) {
            float s1 = z[j] + b1[j];
            t1v = s1 > 0.f ? s1 : 0.f;
        }
    } else {
        if (j < DIM) {
            float s1 = b1[j];
#pragma unroll
            for (int f = 0; f < DIM; ++f) s1 += z[f] * w1[f * DIM + j];
            t1v = s1 > 0.f ? s1 : 0.f;
        }
    }
    float s2 = (j < DIM) ? b2[j] : 0.f;
#pragma unroll
    for (int f = 0; f < DIM; ++f) {
        float tf = __shfl(t1v, base + f, 64);
        if (j < DIM) s2 += tf * w2[f * DIM + j];
    }
    float hv = s2 > 0.f ? s2 : 0.f;

    float hnext = __shfl(hv, base + ((j + 1) & 15), 64);
    if (j < DIM && !(j & 1))
        __builtin_nontemporal_store(pkbf(hv, hnext), &tout[(size_t)i * RSTRIDE + (j >> 1)]);

    if (j < DIM) hp[grp][j] = hv;
    if (j == 0) gid[grp] = batch[i];
    __syncthreads();

    if (tid < DIM) {
        int cg = gid[0];
        float s = hp[0][tid];
        for (int n = 1; n < 16; ++n) {
            int g = gid[n];
            float v = hp[n][tid];
            if (g == cg) s += v;
            else { atomicAdd(&pooled[cg * DIM + tid], s); cg = g; s = v; }
        }
        atomicAdd(&pooled[cg * DIM + tid], s);
    }
}

// ---------- readout ----------
__global__ void final_kernel(const float* __restrict__ pooled,  // [5][G][10]
                             const int* __restrict__ batch,
                             const float* __restrict__ lw,      // [5][10]
                             float* __restrict__ out) {
    int g = blockIdx.x * blockDim.x + threadIdx.x;
    if (g >= NGRAPH) return;
    int lo = 0, hi = N_NODES;
    while (lo < hi) { int m = (lo + hi) >> 1; if (batch[m] < g) lo = m + 1; else hi = m; }
    int a = lo;
    hi = N_NODES;
    while (lo < hi) { int m = (lo + hi) >> 1; if (batch[m] < g + 1) lo = m + 1; else hi = m; }
    float c = (float)(lo - a);
    float inv = 1.0f / (c > 1.f ? c : 1.f);
    float s = 0.f;
#pragma unroll
    for (int l = 0; l < 5; l++) {
        float d = 0.f;
#pragma unroll
        for (int j = 0; j < DIM; j++)
            d += pooled[(size_t)l * NGRAPH * DIM + (size_t)g * DIM + j] * lw[l * DIM + j];
        s += d * inv;
    }
    out[g] = 1.0f / (1.0f + expf(-s));
}

extern "C" void kernel_launch(void* const* d_in, const int* in_sizes, int n_in,
                              void* d_out, int out_size, void* d_ws, size_t ws_size,
                              hipStream_t stream) {
    const float* x    = (const float*)d_in[0];
    const int*   ei   = (const int*)d_in[1];
    const int*   batch= (const int*)d_in[2];
    const float* w1_1 = (const float*)d_in[3];
    const float* b1_1 = (const float*)d_in[4];
    const float* w2_1 = (const float*)d_in[5];
    const float* b2_1 = (const float*)d_in[6];
    const float* ws1  = (const float*)d_in[7];   // [4][10][10]
    const float* bs1  = (const float*)d_in[8];   // [4][10]
    const float* ws2  = (const float*)d_in[9];   // [4][10][10]
    const float* bs2  = (const float*)d_in[10];  // [4][10]
    const float* lw   = (const float*)d_in[11];  // [5][10]
    float* out = (float*)d_out;

    const int* src = ei;
    const int* dst = ei + N_EDGES;

    // ---- workspace layout (u32 units) ----
    int* bstart      = (int*)d_ws;                      // [NB+1]     @0
    unsigned* tot    = (unsigned*)d_ws + 784;           // [NB]       @784
    int* rowstart    = (int*)d_ws + 1568;               // [N+1]      @1568
    unsigned* histg  = (unsigned*)d_ws + 201584;        // [NBLK*NB]  raw counts
    unsigned* wbaseg = histg + (size_t)NBLK * NB;       // [NBLK*NB]  write bases
    unsigned* packed = wbaseg + (size_t)NBLK * NB;      // [E] (dead after node_sort; reused as tA1)
    unsigned* tA1    = packed;                          // overlay: [N*5]
    unsigned* ecol   = packed + N_EDGES;                // [E]
    unsigned* tA0    = ecol + N_EDGES;                  // [N*5]
    float* pooled    = (float*)(tA0 + (size_t)N_NODES * RSTRIDE); // [5][G][10]
    size_t needed = (size_t)((char*)(pooled + 5 * NGRAPH * DIM) - (char*)d_ws);
    if (needed > ws_size) return;  // loud failure (output stays zero)

    const int TB = 256;
    int nblocks = (N_NODES + TB - 1) / TB;
    int gblocks = (NGRAPH + TB - 1) / TB;

    hipMemsetAsync(tot, 0, NB * sizeof(unsigned), stream);
    hipMemsetAsync(pooled, 0, (size_t)5 * NGRAPH * DIM * sizeof(float), stream);

    // ---- build per-node CSR ----
    khist<<<NBLK, STB, 0, stream>>>(dst, histg, tot);
    kscan_tot<<<1, 1024, 0, stream>>>(tot, bstart);
    kscan_wb<<<NB, STB, 0, stream>>>(histg, wbaseg, bstart);
    kscatter<<<NBLK, STB, 0, stream>>>(src, dst, histg, wbaseg, packed);
    node_sort<<<NB, BNODES, 0, stream>>>(packed, bstart, ecol, rowstart);

    // ---- layer 1 (pre-applied w1) ----
    xform_kernel<<<nblocks, TB, 0, stream>>>(x, w1_1, tA0);
    gin_gatherE<true><<<N_NODES / 16, TB, 0, stream>>>(tA0, rowstart, ecol,
        nullptr, b1_1, w2_1, b2_1, batch, tA1, pooled);

    // ---- layers 2..5 (ping-pong) ----
    unsigned *tin = tA1, *tout2 = tA0;
    for (int l = 0; l < 4; l++) {
        gin_gatherE<false><<<N_NODES / 16, TB, 0, stream>>>(tin, rowstart, ecol,
            ws1 + (size_t)l * DIM * DIM, bs1 + (size_t)l * DIM,
            ws2 + (size_t)l * DIM * DIM, bs2 + (size_t)l * DIM,
            batch, tout2, pooled + (size_t)(l + 1) * NGRAPH * DIM);
        unsigned* t = tin; tin = tout2; tout2 = t;
    }

    // ---- readout ----
    final_kernel<<<gblocks, TB, 0, stream>>>(pooled, batch, lw, out);
}